// Round 12
// baseline (853.441 us; speedup 1.0000x reference)
//
#include <hip/hip_runtime.h>

#define D_MODEL 1024
#define SEQ     2048
#define NB      2
#define NH      16
#define HD      64
#define BH      (NB*NH)      // 32
#define M_TOK   (NB*SEQ)     // 4096
#define KSEL    204          // int(2048 * 0.1)
#define TQ      16           // query rows per attention block
#define LCAP    256          // kept-list cap (204 + bin tail headroom)
#define CCAP    96           // candidate-pool cap per row
#define KPW     256          // keys per wave

typedef __attribute__((ext_vector_type(8))) short bf16x8;   // 8 bf16 (4 VGPRs)
typedef __attribute__((ext_vector_type(4))) float f32x4;    // 4 fp32 acc
typedef __attribute__((ext_vector_type(4))) unsigned short us4;

__device__ __forceinline__ unsigned short f2bf(float x) {   // RNE fp32->bf16
    unsigned u = __float_as_uint(x);
    return (unsigned short)((u + 0x7FFFu + ((u >> 16) & 1u)) >> 16);
}
__device__ __forceinline__ float bf2f(unsigned short h) {
    return __uint_as_float(((unsigned)h) << 16);
}

// Bin map on UNSCALED scores d (= s/0.125): one FMA, shared by passes A and B
// so bin assignment is bitwise-consistent.
__device__ __forceinline__ int binOf(float d) {
    int b = (int)__builtin_fmaf(d, 6.125f, 127.4f);
    return b < 0 ? 0 : (b > 255 ? 255 : b);
}

// Fragment-swizzled plane offset (in shorts) for element (n, k) of a
// [N][1024] matrix: tiles of 128 rows x 32 k, fragment order so that a
// wave's global_load_lds(16B) lands lane-contiguous.
__device__ __forceinline__ size_t swzoff(int n, int k) {
    int ntile = n >> 7, ri = n & 127;
    int mi = ri >> 4, rl = ri & 15;
    int kslab = k >> 5, kin = k & 31;
    int ln = rl + ((kin >> 3) << 4);
    return ((size_t)((ntile * 32 + kslab) * 8 + mi)) * 512 + (size_t)ln * 8 + (kin & 7);
}

// async global->LDS DMA, 16 B/lane; LDS dest = wave-uniform base + lane*16
__device__ __forceinline__ void dma16(const unsigned short* g, unsigned short* l) {
    __builtin_amdgcn_global_load_lds(
        (const __attribute__((address_space(1))) unsigned int*)g,
        (__attribute__((address_space(3))) unsigned int*)l,
        16, 0, 0);
}

// ---------------------------------------------------------------------------
// Preconvert all 4 weight matrices -> swizzled hi/lo bf16 planes.
// ---------------------------------------------------------------------------
__global__ __launch_bounds__(256) void preconv_kernel(
    const float* __restrict__ s0, const float* __restrict__ s1,
    const float* __restrict__ s2, const float* __restrict__ s3,
    unsigned short* __restrict__ h0, unsigned short* __restrict__ l0,
    unsigned short* __restrict__ h1, unsigned short* __restrict__ l1,
    unsigned short* __restrict__ h2, unsigned short* __restrict__ l2,
    unsigned short* __restrict__ h3, unsigned short* __restrict__ l3)
{
    const float* src; unsigned short* hi; unsigned short* lo;
    int m = blockIdx.y;
    if (m == 0)      { src = s0; hi = h0; lo = l0; }
    else if (m == 1) { src = s1; hi = h1; lo = l1; }
    else if (m == 2) { src = s2; hi = h2; lo = l2; }
    else             { src = s3; hi = h3; lo = l3; }
    int i = (blockIdx.x * 256 + threadIdx.x) * 4;
    int n = i >> 10, k = i & 1023;
    float4 v = *(const float4*)(src + i);
    float e[4] = {v.x, v.y, v.z, v.w};
    us4 h, l;
#pragma unroll
    for (int t = 0; t < 4; ++t) {
        unsigned short hh = f2bf(e[t]);
        h[t] = hh; l[t] = f2bf(e[t] - bf2f(hh));
    }
    size_t off = swzoff(n, k);
    *(us4*)(hi + off) = h;
    *(us4*)(lo + off) = l;
}

// ---------------------------------------------------------------------------
// Split-bf16 MFMA NT-GEMM. B operand: swizzled planes staged via
// global_load_lds (pure DMA). A operand: AF32=1 -> fp32 + in-kernel convert
// (projections); AF32=0 -> swizzled planes via DMA (oproj).
// MODE 0: fp32 [M][N] out; MODE 1: bf16 head-layout out (v);
// MODE 2: hi/lo head-layout out (q/k).
// ---------------------------------------------------------------------------
template<int MODE, int TERMS, int AF32>
__device__ __forceinline__ void mfma_gemm_body(
    const float* __restrict__ Xf,
    const unsigned short* __restrict__ XHs, const unsigned short* __restrict__ XLs,
    const unsigned short* __restrict__ WHs, const unsigned short* __restrict__ WLs,
    const float* __restrict__ bias,
    float* __restrict__ Cf, unsigned short* __restrict__ Chi,
    unsigned short* __restrict__ Clo, unsigned short* lds)
{
    unsigned short* Ah = lds;
    unsigned short* Al = lds + 4096;
    unsigned short* Bh = lds + 8192;
    unsigned short* Bl = lds + 12288;

    const int tid  = threadIdx.x;
    const int lane = tid & 63;
    const int w    = tid >> 6;
    const int mq   = w & 1;
    const int nq   = w >> 1;
    const int m0   = blockIdx.y * 128;
    const int n0   = blockIdx.x * 128;
    const size_t bbase = (size_t)blockIdx.x * 32 * 4096;
    const size_t abase = (size_t)blockIdx.y * 32 * 4096;

    f32x4 acc[4][4];
#pragma unroll
    for (int i = 0; i < 4; ++i)
#pragma unroll
        for (int j = 0; j < 4; ++j) acc[i][j] = (f32x4){0.f, 0.f, 0.f, 0.f};

    for (int ks = 0; ks < 32; ++ks) {
        float4 xa[4];
        if (AF32) {
#pragma unroll
            for (int r = 0; r < 4; ++r) {
                int f = tid + 256 * r;
                int row = f >> 3, q4 = f & 7;
                xa[r] = *(const float4*)(Xf + (size_t)(m0 + row) * D_MODEL + ks * 32 + q4 * 4);
            }
        }
        __syncthreads();                     // prev iter frag reads done
        {   // B (and A for oproj) via async DMA, fragment-ordered source
            const size_t sb = bbase + (size_t)ks * 4096;
            const int mi0 = w * 2;
            dma16(WHs + sb + (size_t)mi0 * 512 + lane * 8,       Bh + mi0 * 512);
            dma16(WHs + sb + (size_t)(mi0 + 1) * 512 + lane * 8, Bh + (mi0 + 1) * 512);
            dma16(WLs + sb + (size_t)mi0 * 512 + lane * 8,       Bl + mi0 * 512);
            dma16(WLs + sb + (size_t)(mi0 + 1) * 512 + lane * 8, Bl + (mi0 + 1) * 512);
            if (!AF32) {
                const size_t sa = abase + (size_t)ks * 4096;
                dma16(XHs + sa + (size_t)mi0 * 512 + lane * 8,       Ah + mi0 * 512);
                dma16(XHs + sa + (size_t)(mi0 + 1) * 512 + lane * 8, Ah + (mi0 + 1) * 512);
                dma16(XLs + sa + (size_t)mi0 * 512 + lane * 8,       Al + mi0 * 512);
                dma16(XLs + sa + (size_t)(mi0 + 1) * 512 + lane * 8, Al + (mi0 + 1) * 512);
            }
        }
        if (AF32) {
#pragma unroll
            for (int r = 0; r < 4; ++r) {
                int f = tid + 256 * r;
                int row = f >> 3, q4 = f & 7;
                int off = (row >> 4) * 512 + ((row & 15) + (q4 >> 1) * 16) * 8 + (q4 & 1) * 4;
                float ax[4] = {xa[r].x, xa[r].y, xa[r].z, xa[r].w};
                us4 ahv, alv;
#pragma unroll
                for (int e = 0; e < 4; ++e) {
                    unsigned short h1 = f2bf(ax[e]);
                    ahv[e] = h1; alv[e] = f2bf(ax[e] - bf2f(h1));
                }
                *(us4*)(Ah + off) = ahv;  *(us4*)(Al + off) = alv;
            }
        }
        __syncthreads();                     // drains vmcnt (DMA) + lgkm (ds_write)

        bf16x8 fah[4], fal[4], fbh[4], fbl[4];
#pragma unroll
        for (int i = 0; i < 4; ++i) {
            fah[i] = *(const bf16x8*)(Ah + (mq * 4 + i) * 512 + lane * 8);
            fal[i] = *(const bf16x8*)(Al + (mq * 4 + i) * 512 + lane * 8);
            fbh[i] = *(const bf16x8*)(Bh + (nq * 4 + i) * 512 + lane * 8);
            fbl[i] = *(const bf16x8*)(Bl + (nq * 4 + i) * 512 + lane * 8);
        }
#pragma unroll
        for (int i = 0; i < 4; ++i)
#pragma unroll
            for (int j = 0; j < 4; ++j) {
                acc[i][j] = __builtin_amdgcn_mfma_f32_16x16x32_bf16(fah[i], fbh[j], acc[i][j], 0, 0, 0);
                acc[i][j] = __builtin_amdgcn_mfma_f32_16x16x32_bf16(fah[i], fbl[j], acc[i][j], 0, 0, 0);
                acc[i][j] = __builtin_amdgcn_mfma_f32_16x16x32_bf16(fal[i], fbh[j], acc[i][j], 0, 0, 0);
                if (TERMS == 4)
                    acc[i][j] = __builtin_amdgcn_mfma_f32_16x16x32_bf16(fal[i], fbl[j], acc[i][j], 0, 0, 0);
            }
    }

    const int quad = lane >> 4;
    const int rl   = lane & 15;
#pragma unroll
    for (int jt = 0; jt < 4; ++jt) {
        int n = n0 + nq * 64 + jt * 16 + rl;
        float bn = bias[n];
        int h = n >> 6, dd = n & 63;
#pragma unroll
        for (int it = 0; it < 4; ++it) {
#pragma unroll
            for (int r = 0; r < 4; ++r) {
                int m = m0 + mq * 64 + it * 16 + quad * 4 + r;
                float v = acc[it][jt][r] + bn;
                if (MODE == 0) {
                    Cf[(size_t)m * D_MODEL + n] = v;
                } else {
                    int b = m >> 11, s = m & 2047;
                    size_t o = (size_t)(((b << 4) + h) * SEQ + s) * HD + dd;
                    if (MODE == 1) {
                        Chi[o] = f2bf(v);               // v as bf16
                    } else {
                        unsigned short hi = f2bf(v);
                        Chi[o] = hi;
                        Clo[o] = f2bf(v - bf2f(hi));
                    }
                }
            }
        }
    }
}

__global__ __launch_bounds__(256) void proj_qkv_kernel(
    const float* __restrict__ qin, const float* __restrict__ kin, const float* __restrict__ vin,
    const unsigned short* __restrict__ wqh, const unsigned short* __restrict__ wql,
    const unsigned short* __restrict__ wkh, const unsigned short* __restrict__ wkl,
    const unsigned short* __restrict__ wvh, const unsigned short* __restrict__ wvl,
    const float* __restrict__ bq, const float* __restrict__ bk, const float* __restrict__ bv,
    unsigned short* qhi, unsigned short* qlo,
    unsigned short* khi, unsigned short* klo,
    unsigned short* vbf)
{
    __shared__ unsigned short lds[16384];
    if (blockIdx.z == 0)
        mfma_gemm_body<2, 4, 1>(qin, nullptr, nullptr, wqh, wql, bq,
                                nullptr, qhi, qlo, lds);
    else if (blockIdx.z == 1)
        mfma_gemm_body<2, 4, 1>(kin, nullptr, nullptr, wkh, wkl, bk,
                                nullptr, khi, klo, lds);
    else
        mfma_gemm_body<1, 3, 1>(vin, nullptr, nullptr, wvh, wvl, bv,
                                nullptr, vbf, nullptr, lds);
}

__global__ __launch_bounds__(256) void oproj_kernel(
    const unsigned short* __restrict__ AH, const unsigned short* __restrict__ AL,
    const unsigned short* __restrict__ woh, const unsigned short* __restrict__ wol,
    const float* __restrict__ bo, float* __restrict__ out)
{
    __shared__ unsigned short lds[16384];
    mfma_gemm_body<0, 3, 0>(nullptr, AH, AL, woh, wol, bo,
                            out, nullptr, nullptr, lds);
}

// ---------------------------------------------------------------------------
// Attention (round 12): selection identical to rounds 10/11; phase 4 is the
// R10 4-key merged-2-row loop (R11's x2 unroll regressed) with bf16 V loads;
// epilogue writes hi/lo planes in the oproj fragment-swizzled layout.
// ---------------------------------------------------------------------------
__global__ __launch_bounds__(512, 8) void attn_kernel(
    const unsigned short* __restrict__ qhi, const unsigned short* __restrict__ qlo,
    const unsigned short* __restrict__ khi, const unsigned short* __restrict__ klo,
    const unsigned short* __restrict__ vbf,
    unsigned short* __restrict__ awsHi, unsigned short* __restrict__ awsLo)
{
    __shared__ union __align__(16) UU {
        int hist[TQ][260];                          // 16640 B (pass A + scan)
        struct {
            int2  L[TQ][LCAP];                      // 32768 B {key, d_bits}
            float cand[TQ][CCAP];                   // 6144 B
        } p;                                        // 38912 B
    } u;
    __shared__ float thrv[TQ];
    __shared__ int   kneedS[TQ];
    __shared__ int   sbinS[TQ];
    __shared__ int   candCnt[TQ];
    __shared__ int   cnt[TQ];

    const int tid  = threadIdx.x;
    const int lane = tid & 63;
    const int w    = tid >> 6;                      // wave 0..7
    const int quad = lane >> 4;                     // 0..3
    const int rl   = lane & 15;                     // this lane's q row
    const int flat = blockIdx.x;
    const int bh   = (flat & 7) * 4 + ((flat >> 3) & 3);   // XCD swizzle
    const int q0   = (flat >> 5) * TQ;
    const size_t hb = (size_t)bh * SEQ * HD;

    {   // clear histogram + per-row state
        int* hp = &u.hist[0][0];
        for (int i = tid; i < TQ * 260; i += 512) hp[i] = 0;
        if (tid < TQ) { candCnt[tid] = 0; cnt[tid] = 0; }
    }

    // q fragments (B operand; col = q row = rl)
    const size_t qoff = hb + (size_t)(q0 + rl) * HD + quad * 8;
    bf16x8 bqh0 = *(const bf16x8*)(qhi + qoff);
    bf16x8 bql0 = *(const bf16x8*)(qlo + qoff);
    bf16x8 bqh1 = *(const bf16x8*)(qhi + qoff + 32);
    bf16x8 bql1 = *(const bf16x8*)(qlo + qoff + 32);

    const int kbase = w * KPW;
    __syncthreads();                                // clear visible

    // ---- Pass A: unscaled scores -> histogram (discard) ----
#pragma unroll 4
    for (int t = 0; t < 16; ++t) {
        const size_t koff = hb + (size_t)(kbase + t * 16 + rl) * HD + quad * 8;
        bf16x8 ah0 = *(const bf16x8*)(khi + koff);
        bf16x8 al0 = *(const bf16x8*)(klo + koff);
        bf16x8 ah1 = *(const bf16x8*)(khi + koff + 32);
        bf16x8 al1 = *(const bf16x8*)(klo + koff + 32);
        f32x4 d = {0.f, 0.f, 0.f, 0.f};
        d = __builtin_amdgcn_mfma_f32_16x16x32_bf16(ah0, bqh0, d, 0, 0, 0);
        d = __builtin_amdgcn_mfma_f32_16x16x32_bf16(ah0, bql0, d, 0, 0, 0);
        d = __builtin_amdgcn_mfma_f32_16x16x32_bf16(al0, bqh0, d, 0, 0, 0);
        d = __builtin_amdgcn_mfma_f32_16x16x32_bf16(ah1, bqh1, d, 0, 0, 0);
        d = __builtin_amdgcn_mfma_f32_16x16x32_bf16(ah1, bql1, d, 0, 0, 0);
        d = __builtin_amdgcn_mfma_f32_16x16x32_bf16(al1, bqh1, d, 0, 0, 0);
#pragma unroll
        for (int r = 0; r < 4; ++r)
            atomicAdd(&u.hist[rl][binOf(d[r])], 1);
    }
    __syncthreads();

    // ---- Scan: wave w handles rows w, w+8; suffix-sum over 256 bins ----
#pragma unroll
    for (int half = 0; half < 2; ++half) {
        int r = w + half * 8;
        int4 hv = *(const int4*)&u.hist[r][4 * lane];
        int h0 = hv.x, h1 = hv.y, h2 = hv.z, h3 = hv.w;
        int s3 = h3, s2 = h2 + s3, s1 = h1 + s2, s0 = h0 + s1;
        int acc = s0;
#pragma unroll
        for (int off = 1; off < 64; off <<= 1) {
            int v = __shfl_down(acc, off);
            acc += (lane + off < 64) ? v : 0;
        }
        int ehi = acc - s0;
        int suf0 = ehi + s0, suf1 = ehi + s1, suf2 = ehi + s2, suf3 = ehi + s3;
        int selbin = -1, newkn = 0;
        if      (suf3 >= KSEL) { selbin = 4*lane + 3; newkn = KSEL - (suf3 - h3); }
        else if (suf2 >= KSEL) { selbin = 4*lane + 2; newkn = KSEL - (suf2 - h2); }
        else if (suf1 >= KSEL) { selbin = 4*lane + 1; newkn = KSEL - (suf1 - h1); }
        else if (suf0 >= KSEL) { selbin = 4*lane + 0; newkn = KSEL - (suf0 - h0); }
        int pack = ((selbin + 1) << 16) | (newkn & 0xFFFF);
#pragma unroll
        for (int off = 32; off; off >>= 1) {
            int o = __shfl_xor(pack, off);
            pack = pack > o ? pack : o;
        }
        if (lane == 0) {
            sbinS[r]  = (pack >> 16) - 1;
            kneedS[r] = pack & 0xFFFF;
        }
    }
    __syncthreads();                                // hist reads done

    // ---- Pass B: recompute; push {key, d} where bin >= sbin ----
    {
        const int sb = sbinS[rl];
#pragma unroll 4
        for (int t = 0; t < 16; ++t) {
            const size_t koff = hb + (size_t)(kbase + t * 16 + rl) * HD + quad * 8;
            bf16x8 ah0 = *(const bf16x8*)(khi + koff);
            bf16x8 al0 = *(const bf16x8*)(klo + koff);
            bf16x8 ah1 = *(const bf16x8*)(khi + koff + 32);
            bf16x8 al1 = *(const bf16x8*)(klo + koff + 32);
            f32x4 d = {0.f, 0.f, 0.f, 0.f};
            d = __builtin_amdgcn_mfma_f32_16x16x32_bf16(ah0, bqh0, d, 0, 0, 0);
            d = __builtin_amdgcn_mfma_f32_16x16x32_bf16(ah0, bql0, d, 0, 0, 0);
            d = __builtin_amdgcn_mfma_f32_16x16x32_bf16(al0, bqh0, d, 0, 0, 0);
            d = __builtin_amdgcn_mfma_f32_16x16x32_bf16(ah1, bqh1, d, 0, 0, 0);
            d = __builtin_amdgcn_mfma_f32_16x16x32_bf16(ah1, bql1, d, 0, 0, 0);
            d = __builtin_amdgcn_mfma_f32_16x16x32_bf16(al1, bqh1, d, 0, 0, 0);
#pragma unroll
            for (int r = 0; r < 4; ++r) {
                float dv = d[r];
                int b = binOf(dv);
                if (b >= sb) {
                    int key = kbase + t * 16 + quad * 4 + r;
                    int pos = atomicAdd(&cnt[rl], 1);
                    if (pos < LCAP)
                        u.p.L[rl][pos] = make_int2(key, __float_as_int(dv));
                    if (b == sb) {
                        int cp = atomicAdd(&candCnt[rl], 1);
                        if (cp < CCAP) u.p.cand[rl][cp] = dv;
                    }
                }
            }
        }
    }
    __syncthreads();

    // ---- Exact k-th largest among candidates (unscaled): rows w, w+8 ----
#pragma unroll
    for (int half = 0; half < 2; ++half) {
        int r = w + half * 8;
        int n = candCnt[r]; if (n > CCAP) n = CCAP;
        int kn = kneedS[r];
        bool  a0 = lane < n, a1 = lane + 64 < n;
        float x0 = a0 ? u.p.cand[r][lane]      : 0.f;
        float x1 = a1 ? u.p.cand[r][lane + 64] : 0.f;
        int g0 = 0, e0 = 0, g1 = 0, e1 = 0;
        for (int j = 0; j < n; ++j) {
            float c = u.p.cand[r][j];
            g0 += (c > x0);  e0 += (c == x0);
            g1 += (c > x1);  e1 += (c == x1);
        }
        float best = -1e30f;
        if (a0 && g0 < kn && g0 + e0 >= kn) best = x0;
        if (a1 && g1 < kn && g1 + e1 >= kn) best = best > x1 ? best : x1;
#pragma unroll
        for (int off = 32; off; off >>= 1) {
            float o = __shfl_xor(best, off);
            best = best > o ? best : o;
        }
        if (lane == 0) thrv[r] = best;
    }
    __syncthreads();

    // ---- Phase 4: PV gather (4 keys/iter, both rows, bf16 V). ----
    {
        const int b = bh >> 4, h = bh & 15;
        const int slot = lane >> 4;                 // 0..3: key sub-slot
        const int d16  = lane & 15;                 // dim quarter
        const unsigned short* Vp = vbf + hb + d16 * 4;

        const int r0 = w, r1 = w + 8;
        int n0 = cnt[r0]; if (n0 > LCAP) n0 = LCAP;
        int n1 = cnt[r1]; if (n1 > LCAP) n1 = LCAP;
        const float t0 = thrv[r0], t1 = thrv[r1];
        const int nmax = n0 > n1 ? n0 : n1;
        f32x4 a0 = {0.f,0.f,0.f,0.f}, a1 = {0.f,0.f,0.f,0.f};
        float z0 = 0.f, z1 = 0.f;

        for (int j = 0; j < nmax; j += 4) {
            int idx = j + slot;
            int i0 = idx < n0 ? idx : 0;
            int i1 = idx < n1 ? idx : 0;
            int2 p0 = u.p.L[r0][i0];
            int2 p1 = u.p.L[r1][i1];
            float s0 = __int_as_float(p0.y);
            float s1 = __int_as_float(p1.y);
            float w0 = ((idx < n0) && (s0 >= t0))
                       ? __builtin_amdgcn_exp2f((s0 - t0) * 0.1803368801f) : 0.f;
            float w1 = ((idx < n1) && (s1 >= t1))
                       ? __builtin_amdgcn_exp2f((s1 - t1) * 0.1803368801f) : 0.f;
            us4 v0 = *(const us4*)(Vp + (size_t)p0.x * HD);
            us4 v1 = *(const us4*)(Vp + (size_t)p1.x * HD);
            a0[0] += w0 * bf2f(v0[0]); a0[1] += w0 * bf2f(v0[1]);
            a0[2] += w0 * bf2f(v0[2]); a0[3] += w0 * bf2f(v0[3]);
            a1[0] += w1 * bf2f(v1[0]); a1[1] += w1 * bf2f(v1[1]);
            a1[2] += w1 * bf2f(v1[2]); a1[3] += w1 * bf2f(v1[3]);
            z0 += w0; z1 += w1;
        }
#pragma unroll
        for (int off = 16; off < 64; off <<= 1) {
            a0[0] += __shfl_xor(a0[0], off); a0[1] += __shfl_xor(a0[1], off);
            a0[2] += __shfl_xor(a0[2], off); a0[3] += __shfl_xor(a0[3], off);
            a1[0] += __shfl_xor(a1[0], off); a1[1] += __shfl_xor(a1[1], off);
            a1[2] += __shfl_xor(a1[2], off); a1[3] += __shfl_xor(a1[3], off);
            z0 += __shfl_xor(z0, off);       z1 += __shfl_xor(z1, off);
        }
        if (slot == 0) {
            float zr0 = 1.f / z0, zr1 = 1.f / z1;
            float o0[4] = {a0[0]*zr0, a0[1]*zr0, a0[2]*zr0, a0[3]*zr0};
            float o1[4] = {a1[0]*zr1, a1[1]*zr1, a1[2]*zr1, a1[3]*zr1};
            int dcol = h * HD + d16 * 4;
            size_t off0 = swzoff(b * SEQ + q0 + r0, dcol);
            size_t off1 = swzoff(b * SEQ + q0 + r1, dcol);
            us4 h0, l0, h1, l1;
#pragma unroll
            for (int e = 0; e < 4; ++e) {
                unsigned short hh0 = f2bf(o0[e]);
                h0[e] = hh0; l0[e] = f2bf(o0[e] - bf2f(hh0));
                unsigned short hh1 = f2bf(o1[e]);
                h1[e] = hh1; l1[e] = f2bf(o1[e] - bf2f(hh1));
            }
            *(us4*)(awsHi + off0) = h0;  *(us4*)(awsLo + off0) = l0;
            *(us4*)(awsHi + off1) = h1;  *(us4*)(awsLo + off1) = l1;
        }
    }
}

// ---------------------------------------------------------------------------
// Workspace map (60 MB of 64), lifetime-aliased:
//  0-32  : qhi,qlo,khi,klo (proj->attn)
//  32-40 : vbf bf16 (proj->attn)
//  40-52 : Wq/Wk/Wv swizzled planes (preconv->proj)
//  40-56 : awsHi(8)+awsLo(8) swizzled (attn->oproj; aliases dead W planes)
//  56-60 : Wo swizzled planes (preconv->oproj)
// ---------------------------------------------------------------------------
extern "C" void kernel_launch(void* const* d_in, const int* in_sizes, int n_in,
                              void* d_out, int out_size, void* d_ws, size_t ws_size,
                              hipStream_t stream)
{
    const float* query = (const float*)d_in[0];
    const float* key   = (const float*)d_in[1];
    const float* value = (const float*)d_in[2];
    const float* Wq    = (const float*)d_in[3];
    const float* bq    = (const float*)d_in[4];
    const float* Wk    = (const float*)d_in[5];
    const float* bk    = (const float*)d_in[6];
    const float* Wv    = (const float*)d_in[7];
    const float* bv    = (const float*)d_in[8];
    const float* Wo    = (const float*)d_in[9];
    const float* bo    = (const float*)d_in[10];
    float* out = (float*)d_out;

    char* wsb = (char*)d_ws;
    const size_t MB = 1024u * 1024u;
    unsigned short* qhi = (unsigned short*)(wsb);
    unsigned short* qlo = (unsigned short*)(wsb + 8 * MB);
    unsigned short* khi = (unsigned short*)(wsb + 16 * MB);
    unsigned short* klo = (unsigned short*)(wsb + 24 * MB);
    unsigned short* vbf = (unsigned short*)(wsb + 32 * MB);
    unsigned short* wqh = (unsigned short*)(wsb + 40 * MB);
    unsigned short* wql = (unsigned short*)(wsb + 42 * MB);
    unsigned short* wkh = (unsigned short*)(wsb + 44 * MB);
    unsigned short* wkl = (unsigned short*)(wsb + 46 * MB);
    unsigned short* wvh = (unsigned short*)(wsb + 48 * MB);
    unsigned short* wvl = (unsigned short*)(wsb + 50 * MB);
    unsigned short* awsHi = (unsigned short*)(wsb + 40 * MB);
    unsigned short* awsLo = (unsigned short*)(wsb + 48 * MB);
    unsigned short* woh = (unsigned short*)(wsb + 56 * MB);
    unsigned short* wol = (unsigned short*)(wsb + 58 * MB);

    preconv_kernel<<<dim3(1024, 4), 256, 0, stream>>>(
        Wq, Wk, Wv, Wo, wqh, wql, wkh, wkl, wvh, wvl, woh, wol);

    dim3 g1(D_MODEL / 128, M_TOK / 128, 3);
    proj_qkv_kernel<<<g1, 256, 0, stream>>>(query, key, value,
                                            wqh, wql, wkh, wkl, wvh, wvl,
                                            bq, bk, bv,
                                            qhi, qlo, khi, klo, vbf);

    dim3 g2((SEQ / TQ) * BH);
    attn_kernel<<<g2, 512, 0, stream>>>(qhi, qlo, khi, klo, vbf, awsHi, awsLo);

    dim3 g3(D_MODEL / 128, M_TOK / 128);
    oproj_kernel<<<g3, 256, 0, stream>>>(awsHi, awsLo, woh, wol, bo, out);
}